// Round 15
// baseline (1587.989 us; speedup 1.0000x reference)
//
#include <hip/hip_runtime.h>

// LSTM (B=256, T=256, F=128, H=1024) + sigmoid + FC(1024->128).
// Persistent 256-WG x 256-thread kernel (4 waves, 1 wave/SIMD).
// R15 = R14's G=2 skeleton (groups A: rows 0..127, B: rows 128..255 sharing
// register-resident W) with the sync TAIL EMBEDDED in the other group's
// compute phase (R14 left it exposed at end-of-step; MFMA-busy identical
// across R12/13/14 => all deltas are overhead placement):
//  - flagA set at the post-MFMA-B __syncthreads (#4): its vmcnt(0) drains
//    storeA issued ~0.5us earlier -> free drain.
//  - poll flagA + load saA(t) AFTER storeB: the poll's flag-load FIFO-retires
//    storeB (vmcnt retires in order), flagA was set ~0.4us ago -> first-poll
//    hit; saA stays in flight across a PLAIN s_barrier (each wave's poll
//    already proved its own stores drained) into next iter's stage-write.
//  - poll flagB at phase-A top; saB latency covered by stage-write A + MFMA A.
// Flag semantics: flagA[cg]=v <=> h_A(v-1) visible; h_X(s) lives in slot
// (s+1)&3. WAR safe with 4 slots: flagX[q] >= v implies q consumed h(v-3)
// (its stage-write waits its loads before its next flag). Monotonic,
// replay-safe (prep zeroes flags).
// Everything else (fp8 h code, dq k-perm P={0,2,1,3,4,6,5,7}, W*256/x/256
// scale fold, 16x16x32 MFMA tiling, two-stage reduce, swizzles) is
// byte-identical to the R14 kernel that passed at absmax 0.0078.

typedef _Float16 f16x8 __attribute__((ext_vector_type(8)));
typedef float f32x4 __attribute__((ext_vector_type(4)));
typedef unsigned long long u64;
typedef unsigned u32;

#define SCOPE_AGENT __HIP_MEMORY_SCOPE_AGENT

#define WS_WP    0ull
#define WS_BIAS  9437184ull
#define WS_XT    (WS_BIAS + 16384ull)
#define WS_HB    (WS_XT + 16777216ull)          // 2g x 4slot x 8rg x 16KB = 1MB
#define WS_SIGH  (WS_HB + 1048576ull)
#define WS_BAR   (WS_SIGH + 1048576ull)

__device__ __forceinline__ unsigned short f2h(float f) {
  _Float16 h = (_Float16)f;
  return __builtin_bit_cast(unsigned short, h);
}
__device__ __forceinline__ float fast_sig(float x) {
  return __builtin_amdgcn_rcpf(1.f + __expf(-x));
}
__device__ __forceinline__ float fast_tanh(float x) {
  return __builtin_fmaf(2.f, fast_sig(2.f * x), -1.f);
}
__device__ __forceinline__ unsigned char h_enc(float v) {
  _Float16 gh = (_Float16)(v * 0.00390625f);
  unsigned m = __builtin_bit_cast(unsigned short, gh);
  unsigned r = m + 0x3fu + ((m >> 7) & 1u);
  return (unsigned char)(((m >> 8) & 0x80u) | ((r >> 7) & 0x7fu));
}
__device__ __forceinline__ f16x8 dq(u64 v) {
  unsigned w0 = (unsigned)v, w1 = (unsigned)(v >> 32);
  unsigned e0 = w0 & 0x00ff00ffu, o0 = (w0 >> 8) & 0x00ff00ffu;
  unsigned e1 = w1 & 0x00ff00ffu, o1 = (w1 >> 8) & 0x00ff00ffu;
  int4 t;
  t.x = (int)((e0 + (e0 & 0x00800080u)) << 7);
  t.y = (int)((o0 + (o0 & 0x00800080u)) << 7);
  t.z = (int)((e1 + (e1 & 0x00800080u)) << 7);
  t.w = (int)((o1 + (o1 & 0x00800080u)) << 7);
  return __builtin_bit_cast(f16x8, t);
}
// LDS-only barrier: does NOT drain vmcnt (in-flight global loads survive).
__device__ __forceinline__ void lds_barrier() {
  asm volatile("s_waitcnt lgkmcnt(0)" ::: "memory");
  __builtin_amdgcn_s_barrier();
  asm volatile("" ::: "memory");
}

__global__ void prep_pack(const float* __restrict__ W_ih, const float* __restrict__ W_hh,
                          const float* __restrict__ b_ih, const float* __restrict__ b_hh,
                          unsigned short* __restrict__ wp, float* __restrict__ bias) {
  unsigned i = blockIdx.x * 256u + threadIdx.x;
  if (i < 4718592u) {
    unsigned j = i & 7u;
    unsigned l = (i >> 3) & 63u;
    unsigned rest = i >> 9;
    unsigned q = rest % 9u;
    unsigned rest2 = rest / 9u;
    unsigned ct = rest2 & 7u;
    unsigned rest3 = rest2 >> 3;
    unsigned w = rest3 & 3u;
    unsigned cg = rest3 >> 2;
    unsigned gcol = (ct >> 1) * 1024u + cg * 32u + (ct & 1u) * 16u + (l & 15u);
    unsigned khi = (l >> 4) * 8u;
    float v;
    if (q < 8u) {
      unsigned pj = (0x75643120u >> (4u * j)) & 0xfu;   // {0,2,1,3,4,6,5,7}
      unsigned k = w * 256u + q * 32u + khi + pj;
      v = W_hh[(size_t)gcol * 1024u + k];
    } else {
      unsigned f = w * 32u + khi + j;
      v = W_ih[(size_t)gcol * 128u + f];
    }
    wp[i] = f2h(v * 256.0f);
  }
  if (i < 4096u) bias[i] = b_ih[i] + b_hh[i];
}

__global__ void prep_misc(const float* __restrict__ x, const float* __restrict__ h0,
                          unsigned short* __restrict__ xT, unsigned char* __restrict__ hb,
                          unsigned* __restrict__ bar) {
  unsigned i = blockIdx.x * 256u + threadIdx.x;
  if (i < 8388608u) {
    unsigned f = i & 127u;
    unsigned b = (i >> 7) & 255u;
    unsigned t = i >> 15;
    xT[i] = f2h(x[((size_t)b * 256u + t) * 128u + f] * 0.00390625f);
  }
  if (i < 262144u) {
    unsigned col = i & 1023u;
    unsigned grow = i >> 10;
    unsigned g = grow >> 7;
    unsigned rg = (grow >> 4) & 7u;
    unsigned row = grow & 15u;
    hb[((g * 4u + 0u) * 8u + rg) * 16384u + row * 1024u + col] = h_enc(h0[i]);
  }
  if (i < 512u) bar[i] = 0u;
}

#define LOAD_TILE(SA, G, SLOT) do {                                              \
    const char* _b = (const char*)hb + (((G)*4u + (SLOT))*8u + rg)*16384u        \
                     + hi*1024u + w*256u + lo5*8u;                               \
    _Pragma("unroll")                                                            \
    for (int _r = 0; _r < 8; ++_r)                                               \
      SA[_r] = __hip_atomic_load((const u64*)(_b + (unsigned)_r*2048u),          \
                                 __ATOMIC_RELAXED, SCOPE_AGENT);                 \
  } while (0)

#define POLL(FL, TGT) do {                                                       \
    for (;;) {                                                                   \
      unsigned _f = __hip_atomic_load((FL) + w*8u + (l & 7u),                    \
                                      __ATOMIC_RELAXED, SCOPE_AGENT);            \
      if (__all(_f >= (TGT))) break;                                             \
      __builtin_amdgcn_s_sleep(1);                                               \
    }                                                                            \
  } while (0)

__launch_bounds__(256, 1)
__global__ void lstm_main(const unsigned short* __restrict__ wp,
                          const float* __restrict__ bias,
                          const unsigned short* __restrict__ xT,
                          unsigned char* __restrict__ hb,
                          const float* __restrict__ c0,
                          float* __restrict__ sigh,
                          unsigned* __restrict__ bar) {
  extern __shared__ char lds[];
  // [0,16K): per-wave fp8 stage (w*4KB, [16 rows][256B], kbyte^(row&15)<<3)
  // [16K,48K): redv [w4][ct8][l64] float4   [48K,56K): Sf [ct8][reg4][l64] f32
  // [56K..): hstA 512B, hstB 512B
  float4* redv = (float4*)(lds + 16384);
  float*  Sf   = (float*)(lds + 49152);
  unsigned char* hstA = (unsigned char*)(lds + 57344);
  unsigned char* hstB = (unsigned char*)(lds + 57856);

  const unsigned tid = threadIdx.x;
  const unsigned wg  = blockIdx.x;
  const unsigned w   = tid >> 6;
  const unsigned l   = tid & 63u;
  const unsigned rg  = wg >> 5;
  const unsigned cg  = wg & 31u;
  const unsigned lo5 = l & 31u;
  const unsigned hi  = l >> 5;
  const unsigned l15 = l & 15u;
  const unsigned l4  = l >> 4;
  const unsigned row = l4 * 4u + w;            // cell row 0..15 (reg = w)

  // ---- register-resident W fragments (72 x int4) ----
  int4 Braw[8][9];
  {
    const int4* wpv = (const int4*)wp;
    const unsigned wbase = (cg * 4u + w) * 4608u;
#pragma unroll
    for (int ct = 0; ct < 8; ++ct)
#pragma unroll
      for (int q = 0; q < 9; ++q)
        Braw[ct][q] = wpv[wbase + (unsigned)(ct * 9 + q) * 64u + l];
  }

  float bias_v[8];
#pragma unroll
  for (int ct = 0; ct < 8; ++ct)
    bias_v[ct] = bias[(unsigned)(ct >> 1) * 1024u + cg * 32u + (unsigned)(ct & 1) * 16u + l15];

  const unsigned gbA = rg * 16u, gbB = 128u + rg * 16u;
  float cA[2], cB[2];
  unsigned soffA[2], soffB[2];
#pragma unroll
  for (int hh = 0; hh < 2; ++hh) {
    soffA[hh] = (gbA + row) * 1024u + cg * 32u + (unsigned)hh * 16u + l15;
    soffB[hh] = (gbB + row) * 1024u + cg * 32u + (unsigned)hh * 16u + l15;
    cA[hh] = c0[soffA[hh]];
    cB[hh] = c0[soffB[hh]];
  }

  const char* xbase = (const char*)xT;
  const unsigned xoffA = ((gbA + l15) * 128u + w * 32u + l4 * 8u) * 2u;
  const unsigned xoffB = ((gbB + l15) * 128u + w * 32u + l4 * 8u) * 2u;
  unsigned* flagsA = &bar[rg * 32u];
  unsigned* flagsB = &bar[256u + rg * 32u];

  const unsigned fragrow = w * 4096u + l15 * 256u;   // frag read row base

  u64 saA[8], saB[8];
  int4 xrA, xrB;

  LOAD_TILE(saA, 0u, 0u);                 // h_A(-1) = h0, slot 0
  xrA = *(const int4*)(xbase + xoffA);
  xrB = *(const int4*)(xbase + xoffB);

  for (unsigned t = 0; t < 256u; ++t) {
    const bool last = (t == 255u);
    const unsigned slot = t & 3u, wslot = (t + 1u) & 3u;

    // ===== A1: poll B producers for h_B(t-1), then load =====
    POLL(flagsB, t);
    LOAD_TILE(saB, 1u, slot);

    // ===== A2: stage-write A =====
#pragma unroll
    for (int r = 0; r < 8; ++r) {
      unsigned rr = hi + 2u * (unsigned)r;
      unsigned d = w * 4096u + rr * 256u + ((lo5 * 8u) ^ ((rr & 15u) << 3));
      *(u64*)(lds + d) = saA[r];
    }
    lds_barrier();

    // ===== A3: MFMA A (covers saB latency) =====
    f32x4 acc[8] = {};
    {
      f16x8 a = __builtin_bit_cast(f16x8, xrA);
#pragma unroll
      for (int ct = 0; ct < 8; ++ct)
        acc[ct] = __builtin_amdgcn_mfma_f32_16x16x32_f16(a, __builtin_bit_cast(f16x8, Braw[ct][8]), acc[ct], 0, 0, 0);
    }
#pragma unroll
    for (int q = 0; q < 8; ++q) {
      unsigned addr = fragrow + (((unsigned)q * 32u + l4 * 8u) ^ (l15 << 3));
      f16x8 a = dq(*(const u64*)(lds + addr));
#pragma unroll
      for (int ct = 0; ct < 8; ++ct)
        acc[ct] = __builtin_amdgcn_mfma_f32_16x16x32_f16(a, __builtin_bit_cast(f16x8, Braw[ct][q]), acc[ct], 0, 0, 0);
    }

    // ===== reduce A =====
#pragma unroll
    for (int ct = 0; ct < 8; ++ct) {
      float4 v; v.x = acc[ct][0]; v.y = acc[ct][1]; v.z = acc[ct][2]; v.w = acc[ct][3];
      redv[(w * 8u + (unsigned)ct) * 64u + l] = v;
    }
    lds_barrier();
#pragma unroll
    for (int c2 = 0; c2 < 2; ++c2) {
      unsigned ct = 2u * w + (unsigned)c2;
      float4 s = redv[ct * 64u + l];
#pragma unroll
      for (int wo = 1; wo < 4; ++wo) {
        float4 v = redv[((unsigned)wo * 8u + ct) * 64u + l];
        s.x += v.x; s.y += v.y; s.z += v.z; s.w += v.w;
      }
      Sf[ct * 256u + 0u * 64u + l] = s.x;
      Sf[ct * 256u + 1u * 64u + l] = s.y;
      Sf[ct * 256u + 2u * 64u + l] = s.z;
      Sf[ct * 256u + 3u * 64u + l] = s.w;
    }
    lds_barrier();
    float gv[8];
#pragma unroll
    for (int ct = 0; ct < 8; ++ct)
      gv[ct] = Sf[(unsigned)ct * 256u + w * 64u + l] + bias_v[ct];
#pragma unroll
    for (int hh = 0; hh < 2; ++hh) {
      float ig = fast_sig(gv[0 * 2 + hh]);
      float fg = fast_sig(gv[1 * 2 + hh]);
      float gg = fast_tanh(gv[2 * 2 + hh]);
      float og = fast_sig(gv[3 * 2 + hh]);
      float cc = fg * cA[hh] + ig * gg;
      cA[hh] = cc;
      float hhv = og * fast_tanh(cc);
      hstA[row * 32u + (unsigned)hh * 16u + l15] = h_enc(hhv);
      if (last) sigh[soffA[hh]] = fast_sig(hhv);
    }
    lds_barrier();
    // A7: store h_A(t) (ACK hidden under B's stage+MFMA, drained at #4)
    if (!last && tid < 128u) {
      u32 v = *(const u32*)(hstA + (tid >> 3) * 32u + (tid & 7u) * 4u);
      char* dst = (char*)hb + ((0u * 4u + wslot) * 8u + rg) * 16384u
                  + (tid >> 3) * 1024u + cg * 32u + (tid & 7u) * 4u;
      __hip_atomic_store((u32*)dst, v, __ATOMIC_RELAXED, SCOPE_AGENT);
    }

    // ===== B1: stage-write B (stage region free since redvA barrier) =====
#pragma unroll
    for (int r = 0; r < 8; ++r) {
      unsigned rr = hi + 2u * (unsigned)r;
      unsigned d = w * 4096u + rr * 256u + ((lo5 * 8u) ^ ((rr & 15u) << 3));
      *(u64*)(lds + d) = saB[r];
    }
    lds_barrier();

    // ===== B2: MFMA B =====
    f32x4 accB[8] = {};
    {
      f16x8 a = __builtin_bit_cast(f16x8, xrB);
#pragma unroll
      for (int ct = 0; ct < 8; ++ct)
        accB[ct] = __builtin_amdgcn_mfma_f32_16x16x32_f16(a, __builtin_bit_cast(f16x8, Braw[ct][8]), accB[ct], 0, 0, 0);
    }
#pragma unroll
    for (int q = 0; q < 8; ++q) {
      unsigned addr = fragrow + (((unsigned)q * 32u + l4 * 8u) ^ (l15 << 3));
      f16x8 a = dq(*(const u64*)(lds + addr));
#pragma unroll
      for (int ct = 0; ct < 8; ++ct)
        accB[ct] = __builtin_amdgcn_mfma_f32_16x16x32_f16(a, __builtin_bit_cast(f16x8, Braw[ct][q]), accB[ct], 0, 0, 0);
    }
#pragma unroll
    for (int ct = 0; ct < 8; ++ct) {
      float4 v; v.x = accB[ct][0]; v.y = accB[ct][1]; v.z = accB[ct][2]; v.w = accB[ct][3];
      redv[(w * 8u + (unsigned)ct) * 64u + l] = v;
    }
    // #4: full barrier = redvB visible AND storeA drained (free: issued ~0.5us ago)
    __syncthreads();
    if (!last && tid == 0)
      __hip_atomic_store(&flagsA[cg], t + 1u, __ATOMIC_RELAXED, SCOPE_AGENT);

#pragma unroll
    for (int c2 = 0; c2 < 2; ++c2) {
      unsigned ct = 2u * w + (unsigned)c2;
      float4 s = redv[ct * 64u + l];
#pragma unroll
      for (int wo = 1; wo < 4; ++wo) {
        float4 v = redv[((unsigned)wo * 8u + ct) * 64u + l];
        s.x += v.x; s.y += v.y; s.z += v.z; s.w += v.w;
      }
      Sf[ct * 256u + 0u * 64u + l] = s.x;
      Sf[ct * 256u + 1u * 64u + l] = s.y;
      Sf[ct * 256u + 2u * 64u + l] = s.z;
      Sf[ct * 256u + 3u * 64u + l] = s.w;
    }
    lds_barrier();
#pragma unroll
    for (int ct = 0; ct < 8; ++ct)
      gv[ct] = Sf[(unsigned)ct * 256u + w * 64u + l] + bias_v[ct];
#pragma unroll
    for (int hh = 0; hh < 2; ++hh) {
      float ig = fast_sig(gv[0 * 2 + hh]);
      float fg = fast_sig(gv[1 * 2 + hh]);
      float gg = fast_tanh(gv[2 * 2 + hh]);
      float og = fast_sig(gv[3 * 2 + hh]);
      float cc = fg * cB[hh] + ig * gg;
      cB[hh] = cc;
      float hhv = og * fast_tanh(cc);
      hstB[row * 32u + (unsigned)hh * 16u + l15] = h_enc(hhv);
      if (last) sigh[soffB[hh]] = fast_sig(hhv);
    }
    lds_barrier();

    if (!last) {
      // B6: store h_B(t)
      if (tid < 128u) {
        u32 v = *(const u32*)(hstB + (tid >> 3) * 32u + (tid & 7u) * 4u);
        char* dst = (char*)hb + ((1u * 4u + wslot) * 8u + rg) * 16384u
                    + (tid >> 3) * 1024u + cg * 32u + (tid & 7u) * 4u;
        __hip_atomic_store((u32*)dst, v, __ATOMIC_RELAXED, SCOPE_AGENT);
      }
      // B7: poll flagA (set at #4 ~0.4us ago -> first-poll hit).
      // The poll's flag-load FIFO-retires this wave's storeB for free.
      POLL(flagsA, t + 1u);
      // saA(t) loads: fly across the plain barrier into next iter's stage-write
      LOAD_TILE(saA, 0u, wslot);
      xrA = *(const int4*)(xbase + xoffA + (t + 1u) * 65536u);
      xrB = *(const int4*)(xbase + xoffB + (t + 1u) * 65536u);
      // plain barrier: every wave passed its poll => its storeB is drained
      lds_barrier();
      if (tid == 0)
        __hip_atomic_store(&flagsB[cg], t + 1u, __ATOMIC_RELAXED, SCOPE_AGENT);
    }
  }
}

// out[b][o] = b_fc[o] + sum_k sigh[b][k] * W_fc[o][k]
__global__ void final_fc(const float* __restrict__ sigh, const float* __restrict__ W_fc,
                         const float* __restrict__ b_fc, float* __restrict__ out) {
  unsigned b = blockIdx.x;
  unsigned o = threadIdx.x;
  const float* hrow = sigh + (size_t)b * 1024u;
  const float* wrow = W_fc + (size_t)o * 1024u;
  float acc = b_fc[o];
#pragma unroll 8
  for (unsigned k = 0; k < 1024u; k += 4u) {
    float4 hv = *(const float4*)(hrow + k);
    float4 wv = *(const float4*)(wrow + k);
    acc += hv.x * wv.x + hv.y * wv.y + hv.z * wv.z + hv.w * wv.w;
  }
  out[b * 128u + o] = acc;
}

extern "C" void kernel_launch(void* const* d_in, const int* in_sizes, int n_in,
                              void* d_out, int out_size, void* d_ws, size_t ws_size,
                              hipStream_t stream) {
  (void)in_sizes; (void)n_in; (void)out_size; (void)ws_size;
  const float* x    = (const float*)d_in[0];
  const float* h0   = (const float*)d_in[1];
  const float* c0   = (const float*)d_in[2];
  const float* W_ih = (const float*)d_in[3];
  const float* W_hh = (const float*)d_in[4];
  const float* b_ih = (const float*)d_in[5];
  const float* b_hh = (const float*)d_in[6];
  const float* W_fc = (const float*)d_in[7];
  const float* b_fc = (const float*)d_in[8];

  char* ws = (char*)d_ws;
  unsigned short* wp   = (unsigned short*)(ws + WS_WP);
  float*          bias = (float*)(ws + WS_BIAS);
  unsigned short* xT   = (unsigned short*)(ws + WS_XT);
  unsigned char*  hb   = (unsigned char*)(ws + WS_HB);
  float*          sigh = (float*)(ws + WS_SIGH);
  unsigned*       bar  = (unsigned*)(ws + WS_BAR);
  float*          out  = (float*)d_out;

  prep_pack<<<18432, 256, 0, stream>>>(W_ih, W_hh, b_ih, b_hh, wp, bias);
  prep_misc<<<32768, 256, 0, stream>>>(x, h0, xT, hb, bar);
  lstm_main<<<256, 256, 58368, stream>>>(wp, bias, xT, hb, c0, sigh, bar);
  final_fc<<<256, 128, 0, stream>>>(sigh, W_fc, b_fc, out);
}